// Round 11
// baseline (716.176 us; speedup 1.0000x reference)
//
#include <hip/hip_runtime.h>

#define NN 50000
#define NE 800000
#define NNP 50176           // NN padded to 196*256
#define EPSV 1e-5f

// ---------------- CSR build: histogram ----------------
__global__ void hist_kernel(const int* __restrict__ dst, int* __restrict__ cnt, int ne) {
    int e = blockIdx.x * blockDim.x + threadIdx.x;
    if (e < ne) atomicAdd(&cnt[dst[e]], 1);
}

// ---------------- CSR build: 3-phase exclusive scan over NNP elements ----------------
__global__ void scan1_kernel(const int* __restrict__ cnt, int* __restrict__ row_ptr,
                             int* __restrict__ bsum) {
    __shared__ int s[256];
    int i = blockIdx.x * 256 + threadIdx.x;
    int v = cnt[i];
    s[threadIdx.x] = v;
    __syncthreads();
    #pragma unroll
    for (int off = 1; off < 256; off <<= 1) {
        int t = (threadIdx.x >= off) ? s[threadIdx.x - off] : 0;
        __syncthreads();
        s[threadIdx.x] += t;
        __syncthreads();
    }
    row_ptr[i] = s[threadIdx.x] - v;           // exclusive within block
    if (threadIdx.x == 255) bsum[blockIdx.x] = s[255];
}

__global__ void scan2_kernel(int* __restrict__ bsum, int nb) {
    __shared__ int s[256];
    int v = (threadIdx.x < nb) ? bsum[threadIdx.x] : 0;
    s[threadIdx.x] = v;
    __syncthreads();
    #pragma unroll
    for (int off = 1; off < 256; off <<= 1) {
        int t = (threadIdx.x >= off) ? s[threadIdx.x - off] : 0;
        __syncthreads();
        s[threadIdx.x] += t;
        __syncthreads();
    }
    if (threadIdx.x < nb) bsum[threadIdx.x] = s[threadIdx.x] - v;  // exclusive
}

__global__ void scan3_kernel(int* __restrict__ row_ptr, const int* __restrict__ bsum,
                             int* __restrict__ fill) {
    int i = blockIdx.x * 256 + threadIdx.x;
    int v = row_ptr[i] + bsum[blockIdx.x];
    row_ptr[i] = v;
    if (i < NN) fill[i] = v;   // running insert cursors start at row offsets
}

// ---------------- CSR build: bucket fill ----------------
__global__ void fill_kernel(const int* __restrict__ src, const int* __restrict__ dst,
                            int* __restrict__ fill, int* __restrict__ eidx, int ne) {
    int e = blockIdx.x * blockDim.x + threadIdx.x;
    if (e >= ne) return;
    int pos = atomicAdd(&fill[dst[e]], 1);
    eidx[pos] = src[e];
}

__device__ __forceinline__ void act4(float4& v, const float4& sc, const float4& sh) {
    v.x = fmaxf(fmaf(v.x, sc.x, sh.x), 0.f);
    v.y = fmaxf(fmaf(v.y, sc.y, sh.y), 0.f);
    v.z = fmaxf(fmaf(v.z, sc.z, sh.z), 0.f);
    v.w = fmaxf(fmaf(v.w, sc.w, sh.w), 0.f);
}
__device__ __forceinline__ void add4(float4& a, const float4& v) {
    a.x += v.x; a.y += v.y; a.z += v.z; a.w += v.w;
}

// ---------------- gather mean-aggregation (layers 2/3) ----------------
// agg[n] = mean_{s in adj(n)} act(x[s]); act = relu(v*sc+sh) if AFF.
// Edge loop unrolled x4, 4 accumulators for memory-level parallelism.
template<int F, bool AFF>
__global__ __launch_bounds__(256) void gather_kernel(
    const float* __restrict__ x, const int* __restrict__ row_ptr,
    const int* __restrict__ eidx, float* __restrict__ agg,
    const float* __restrict__ ss) {
    constexpr int TPN = F / 4;
    constexpr int NPB = 256 / TPN;
    int t = threadIdx.x;
    int node = blockIdx.x * NPB + t / TPN;
    if (node >= NN) return;
    int f = (t % TPN) * 4;
    float4 sc = make_float4(1.f, 1.f, 1.f, 1.f);
    float4 sh = make_float4(0.f, 0.f, 0.f, 0.f);
    if constexpr (AFF) {
        sc = *reinterpret_cast<const float4*>(&ss[f]);
        sh = *reinterpret_cast<const float4*>(&ss[F + f]);
    }
    int beg = row_ptr[node], end = row_ptr[node + 1];
    float4 a0 = make_float4(0.f,0.f,0.f,0.f), a1 = a0, a2 = a0, a3 = a0;
    int i = beg;
    for (; i + 3 < end; i += 4) {
        int s0 = eidx[i], s1 = eidx[i+1], s2 = eidx[i+2], s3 = eidx[i+3];
        float4 v0 = *reinterpret_cast<const float4*>(x + (size_t)s0 * F + f);
        float4 v1 = *reinterpret_cast<const float4*>(x + (size_t)s1 * F + f);
        float4 v2 = *reinterpret_cast<const float4*>(x + (size_t)s2 * F + f);
        float4 v3 = *reinterpret_cast<const float4*>(x + (size_t)s3 * F + f);
        if constexpr (AFF) { act4(v0,sc,sh); act4(v1,sc,sh); act4(v2,sc,sh); act4(v3,sc,sh); }
        add4(a0,v0); add4(a1,v1); add4(a2,v2); add4(a3,v3);
    }
    for (; i < end; i++) {
        int s0 = eidx[i];
        float4 v0 = *reinterpret_cast<const float4*>(x + (size_t)s0 * F + f);
        if constexpr (AFF) act4(v0,sc,sh);
        add4(a0,v0);
    }
    add4(a0,a1); add4(a2,a3); add4(a0,a2);
    float inv = 1.0f / (float)max(end - beg, 1);
    a0.x *= inv; a0.y *= inv; a0.z *= inv; a0.w *= inv;
    *reinterpret_cast<float4*>(agg + (size_t)node * F + f) = a0;
}

// ---------------- layer-1 gather-add: h1 = mean(xp[s]) + xr[n], + BN stats ----------------
// xp = x@W1l (no bias), xr = x@W1r + b1. F fixed at 64. Grid exactly 3125x256.
__global__ __launch_bounds__(256) void gather_add_kernel(
    const float* __restrict__ xp, const float* __restrict__ xr,
    const int* __restrict__ row_ptr, const int* __restrict__ eidx,
    float* __restrict__ h, float* __restrict__ stats) {
    __shared__ float sStat[128];
    int t = threadIdx.x;
    if (t < 128) sStat[t] = 0.f;
    __syncthreads();
    int node = blockIdx.x * 16 + t / 16;   // always < NN (grid exact)
    int f = (t % 16) * 4;
    int beg = row_ptr[node], end = row_ptr[node + 1];
    float4 a0 = make_float4(0.f,0.f,0.f,0.f), a1 = a0, a2 = a0, a3 = a0;
    int i = beg;
    for (; i + 3 < end; i += 4) {
        int s0 = eidx[i], s1 = eidx[i+1], s2 = eidx[i+2], s3 = eidx[i+3];
        add4(a0, *reinterpret_cast<const float4*>(xp + (size_t)s0 * 64 + f));
        add4(a1, *reinterpret_cast<const float4*>(xp + (size_t)s1 * 64 + f));
        add4(a2, *reinterpret_cast<const float4*>(xp + (size_t)s2 * 64 + f));
        add4(a3, *reinterpret_cast<const float4*>(xp + (size_t)s3 * 64 + f));
    }
    for (; i < end; i++)
        add4(a0, *reinterpret_cast<const float4*>(xp + (size_t)eidx[i] * 64 + f));
    add4(a0,a1); add4(a2,a3); add4(a0,a2);
    float inv = 1.0f / (float)max(end - beg, 1);
    float4 o = *reinterpret_cast<const float4*>(xr + (size_t)node * 64 + f);
    o.x = fmaf(a0.x, inv, o.x);
    o.y = fmaf(a0.y, inv, o.y);
    o.z = fmaf(a0.z, inv, o.z);
    o.w = fmaf(a0.w, inv, o.w);
    *reinterpret_cast<float4*>(h + (size_t)node * 64 + f) = o;
    atomicAdd(&sStat[f + 0], o.x);      atomicAdd(&sStat[64 + f + 0], o.x * o.x);
    atomicAdd(&sStat[f + 1], o.y);      atomicAdd(&sStat[64 + f + 1], o.y * o.y);
    atomicAdd(&sStat[f + 2], o.z);      atomicAdd(&sStat[64 + f + 2], o.z * o.z);
    atomicAdd(&sStat[f + 3], o.w);      atomicAdd(&sStat[64 + f + 3], o.w * o.w);
    __syncthreads();
    if (t < 128) unsafeAtomicAdd(&stats[t], sStat[t]);
}

// Macro params avoid collision with .x/.y/.z/.w member tokens.
#define FMA4(A_, W_, S_) { S_[0]=fmaf(A_,(W_).x,S_[0]); S_[1]=fmaf(A_,(W_).y,S_[1]); \
                           S_[2]=fmaf(A_,(W_).z,S_[2]); S_[3]=fmaf(A_,(W_).w,S_[3]); }

// ---------------- fused GEMM with T14 reg-prefetch staging ----------------
// Normal:  y = agg@Wagg + bias + act(x)@Wroot (+BN stats).
// DUAL:    y = x@Wroot (no bias), y2 = x@Wagg + bias  (x staged once, two W mats).
// k-loop: write regs->LDS, barrier, ISSUE next-tile loads, compute, barrier.
template<int K, int N, int NB, int ROWS, bool HAS_AGG, bool BN, bool AFFX, bool DUAL>
__global__ __launch_bounds__(256, 4) void gemm_kernel(
    const float* __restrict__ xin, const float* __restrict__ agg,
    const float* __restrict__ Wroot, const float* __restrict__ Wagg,
    const float* __restrict__ bias, const float* __restrict__ ssx,
    float* __restrict__ y, float* __restrict__ y2,
    float* __restrict__ stats, int M)
{
    constexpr int  Kc    = 16;
    constexpr int  CG    = NB / 4;
    constexpr int  RT    = 256 / CG;
    constexpr int  RPT   = ROWS / RT;
    constexpr int  XP    = Kc + 4;
    constexpr bool W2    = HAS_AGG || DUAL;
    constexpr int  WLOAD = (Kc * NB / 4) / 256;     // float4 per thread per W mat
    constexpr int  XLOAD = (ROWS * (Kc / 4)) / 256; // float4 per thread per X mat

    __shared__ float sWr[Kc * NB];
    __shared__ float sWa[W2 ? Kc * NB : 1];
    __shared__ float sX [ROWS * XP];
    __shared__ float sA [HAS_AGG ? ROWS * XP : 1];
    __shared__ float sStat[BN ? 2 * NB : 1];

    const int tid  = threadIdx.x;
    const int tx   = tid % CG;
    const int ty   = tid / CG;
    const int row0 = blockIdx.x * ROWS;
    const int col0 = blockIdx.y * NB;

    float acc[RPT][4];
    float acc2[DUAL ? RPT : 1][4];
    #pragma unroll
    for (int i = 0; i < RPT; i++) { acc[i][0]=0.f; acc[i][1]=0.f; acc[i][2]=0.f; acc[i][3]=0.f; }
    if constexpr (DUAL) {
        #pragma unroll
        for (int i = 0; i < RPT; i++) { acc2[i][0]=0.f; acc2[i][1]=0.f; acc2[i][2]=0.f; acc2[i][3]=0.f; }
    }

    float4 rW[WLOAD], rWa[W2 ? WLOAD : 1], rX[XLOAD], rA[HAS_AGG ? XLOAD : 1];

    auto load_tile = [&](int k0) {
        #pragma unroll
        for (int u = 0; u < WLOAD; u++) {
            int idx = (tid + u * 256) * 4;
            int r = idx / NB, c = idx % NB;
            rW[u] = *reinterpret_cast<const float4*>(&Wroot[(size_t)(k0 + r) * N + col0 + c]);
            if constexpr (W2)
                rWa[u] = *reinterpret_cast<const float4*>(&Wagg[(size_t)(k0 + r) * N + col0 + c]);
        }
        #pragma unroll
        for (int u = 0; u < XLOAD; u++) {
            int idx = tid + u * 256;
            int r = idx / (Kc / 4);
            int c = (idx % (Kc / 4)) * 4;
            int grow = row0 + r;
            float4 z = make_float4(0.f, 0.f, 0.f, 0.f);
            rX[u] = z;
            if constexpr (HAS_AGG) rA[u] = z;
            if (grow < M) {
                rX[u] = *reinterpret_cast<const float4*>(&xin[(size_t)grow * K + k0 + c]);
                if constexpr (HAS_AGG)
                    rA[u] = *reinterpret_cast<const float4*>(&agg[(size_t)grow * K + k0 + c]);
            }
        }
    };

    auto store_tile = [&](int k0) {
        #pragma unroll
        for (int u = 0; u < WLOAD; u++) {
            int idx = (tid + u * 256) * 4;
            int r = idx / NB, c = idx % NB;
            *reinterpret_cast<float4*>(&sWr[r * NB + c]) = rW[u];
            if constexpr (W2) *reinterpret_cast<float4*>(&sWa[r * NB + c]) = rWa[u];
        }
        #pragma unroll
        for (int u = 0; u < XLOAD; u++) {
            int idx = tid + u * 256;
            int r = idx / (Kc / 4);
            int c = (idx % (Kc / 4)) * 4;
            float4 xv = rX[u];
            if constexpr (AFFX) {
                float4 sc = *reinterpret_cast<const float4*>(&ssx[k0 + c]);
                float4 sh = *reinterpret_cast<const float4*>(&ssx[K + k0 + c]);
                act4(xv, sc, sh);
            }
            *reinterpret_cast<float4*>(&sX[r * XP + c]) = xv;
            if constexpr (HAS_AGG) *reinterpret_cast<float4*>(&sA[r * XP + c]) = rA[u];
        }
    };

    load_tile(0);
    for (int k0 = 0; k0 < K; k0 += Kc) {
        store_tile(k0);
        __syncthreads();
        if (k0 + Kc < K) load_tile(k0 + Kc);   // issue next tile; latency hides under compute

        #pragma unroll
        for (int kk0 = 0; kk0 < Kc; kk0 += 4) {
            float4 wr0 = *reinterpret_cast<const float4*>(&sWr[(kk0 + 0) * NB + tx * 4]);
            float4 wr1 = *reinterpret_cast<const float4*>(&sWr[(kk0 + 1) * NB + tx * 4]);
            float4 wr2 = *reinterpret_cast<const float4*>(&sWr[(kk0 + 2) * NB + tx * 4]);
            float4 wr3 = *reinterpret_cast<const float4*>(&sWr[(kk0 + 3) * NB + tx * 4]);
            float4 wa0, wa1, wa2, wa3;
            if constexpr (W2) {
                wa0 = *reinterpret_cast<const float4*>(&sWa[(kk0 + 0) * NB + tx * 4]);
                wa1 = *reinterpret_cast<const float4*>(&sWa[(kk0 + 1) * NB + tx * 4]);
                wa2 = *reinterpret_cast<const float4*>(&sWa[(kk0 + 2) * NB + tx * 4]);
                wa3 = *reinterpret_cast<const float4*>(&sWa[(kk0 + 3) * NB + tx * 4]);
            }
            #pragma unroll
            for (int i = 0; i < RPT; i++) {
                int r = ty + i * RT;
                float4 xv = *reinterpret_cast<const float4*>(&sX[r * XP + kk0]);
                FMA4(xv.x, wr0, acc[i]);
                FMA4(xv.y, wr1, acc[i]);
                FMA4(xv.z, wr2, acc[i]);
                FMA4(xv.w, wr3, acc[i]);
                if constexpr (HAS_AGG) {
                    float4 av = *reinterpret_cast<const float4*>(&sA[r * XP + kk0]);
                    FMA4(av.x, wa0, acc[i]);
                    FMA4(av.y, wa1, acc[i]);
                    FMA4(av.z, wa2, acc[i]);
                    FMA4(av.w, wa3, acc[i]);
                } else if constexpr (DUAL) {
                    FMA4(xv.x, wa0, acc2[i]);
                    FMA4(xv.y, wa1, acc2[i]);
                    FMA4(xv.z, wa2, acc2[i]);
                    FMA4(xv.w, wa3, acc2[i]);
                }
            }
        }
        __syncthreads();
    }

    float4 bv = *reinterpret_cast<const float4*>(&bias[col0 + tx * 4]);

    if constexpr (DUAL) {
        #pragma unroll
        for (int i = 0; i < RPT; i++) {
            int grow = row0 + ty + i * RT;
            if (grow < M) {
                float4 o1 = make_float4(acc[i][0], acc[i][1], acc[i][2], acc[i][3]);
                float4 o2 = make_float4(acc2[i][0] + bv.x, acc2[i][1] + bv.y,
                                        acc2[i][2] + bv.z, acc2[i][3] + bv.w);
                *reinterpret_cast<float4*>(&y [(size_t)grow * N + col0 + tx * 4]) = o1;
                *reinterpret_cast<float4*>(&y2[(size_t)grow * N + col0 + tx * 4]) = o2;
            }
        }
        return;
    }

    if constexpr (BN) {
        for (int idx = tid; idx < 2 * NB; idx += 256) sStat[idx] = 0.f;
        __syncthreads();
    }

    float cs[4] = {0.f,0.f,0.f,0.f}, cq[4] = {0.f,0.f,0.f,0.f};
    #pragma unroll
    for (int i = 0; i < RPT; i++) {
        int grow = row0 + ty + i * RT;
        if (grow < M) {
            float4 o;
            o.x = acc[i][0] + bv.x;
            o.y = acc[i][1] + bv.y;
            o.z = acc[i][2] + bv.z;
            o.w = acc[i][3] + bv.w;
            *reinterpret_cast<float4*>(&y[(size_t)grow * N + col0 + tx * 4]) = o;
            if constexpr (BN) {
                cs[0] += o.x; cq[0] += o.x * o.x;
                cs[1] += o.y; cq[1] += o.y * o.y;
                cs[2] += o.z; cq[2] += o.z * o.z;
                cs[3] += o.w; cq[3] += o.w * o.w;
            }
        }
    }

    if constexpr (BN) {
        atomicAdd(&sStat[tx * 4 + 0], cs[0]);
        atomicAdd(&sStat[tx * 4 + 1], cs[1]);
        atomicAdd(&sStat[tx * 4 + 2], cs[2]);
        atomicAdd(&sStat[tx * 4 + 3], cs[3]);
        atomicAdd(&sStat[NB + tx * 4 + 0], cq[0]);
        atomicAdd(&sStat[NB + tx * 4 + 1], cq[1]);
        atomicAdd(&sStat[NB + tx * 4 + 2], cq[2]);
        atomicAdd(&sStat[NB + tx * 4 + 3], cq[3]);
        __syncthreads();
        for (int idx = tid; idx < 2 * NB; idx += 256) {
            int gidx = (idx < NB) ? (col0 + idx) : (N + col0 + idx - NB);
            unsafeAtomicAdd(&stats[gidx], sStat[idx]);
        }
    }
}

// ---------------- BN finalize: scale/shift per column ----------------
__global__ void bnfin_kernel(const float* __restrict__ stats, const float* __restrict__ g,
                             const float* __restrict__ be, float* __restrict__ ss,
                             int N, float invM) {
    int c = threadIdx.x;
    if (c >= N) return;
    float mean = stats[c] * invM;
    float var  = stats[N + c] * invM - mean * mean;
    float sc   = g[c] * rsqrtf(fmaxf(var, 0.f) + EPSV);
    ss[c]     = sc;
    ss[N + c] = be[c] - mean * sc;
}

extern "C" void kernel_launch(void* const* d_in, const int* in_sizes, int n_in,
                              void* d_out, int out_size, void* d_ws, size_t ws_size,
                              hipStream_t stream) {
    const float* x   = (const float*)d_in[0];
    const int*   ei  = (const int*)d_in[1];
    const int*   src = ei;
    const int*   dst = ei + NE;
    const float *W1l = (const float*)d_in[2],  *b1 = (const float*)d_in[3],
                *W1r = (const float*)d_in[4],  *g1 = (const float*)d_in[5],  *be1 = (const float*)d_in[6];
    const float *W2l = (const float*)d_in[7],  *b2 = (const float*)d_in[8],
                *W2r = (const float*)d_in[9],  *g2 = (const float*)d_in[10], *be2 = (const float*)d_in[11];
    const float *W3l = (const float*)d_in[12], *b3 = (const float*)d_in[13],
                *W3r = (const float*)d_in[14], *g3 = (const float*)d_in[15], *be3 = (const float*)d_in[16];
    const float *Wp  = (const float*)d_in[17], *bp = (const float*)d_in[18];

    char* w = (char*)d_ws;
    size_t off = 0;
    auto alloc = [&](size_t bytes) { char* p = w + off; off += (bytes + 255) & ~255ULL; return p; };

    int*   cnt     = (int*)  alloc(NNP * 4);          // zeroed
    float* stats   = (float*)alloc(1536 * 4);         // zeroed
    size_t zero_bytes = off;
    float* ss      = (float*)alloc(1536 * 4);
    int*   row_ptr = (int*)  alloc((NNP + 1) * 4);
    int*   fillc   = (int*)  alloc(NNP * 4);
    int*   bsum    = (int*)  alloc(256 * 4);
    int*   eidx    = (int*)  alloc((size_t)NE * 4);
    float* agg     = (float*)alloc((size_t)NN * 128 * 4);
    float* h1      = (float*)alloc((size_t)NN * 64 * 4);
    float* h2      = (float*)alloc((size_t)NN * 128 * 4);
    float* h3      = (float*)alloc((size_t)NN * 256 * 4);

    float* ss1 = ss + 0;     // [64 sc | 64 sh]
    float* ss2 = ss + 512;   // [128 sc | 128 sh]
    float* ss3 = ss + 1024;  // [256 sc | 256 sh]
    float* xp  = agg;                    // NN*64, dead before L2 gather reuses agg
    float* xr  = agg + (size_t)NN * 64;  // NN*64

    (void)hipMemsetAsync(d_ws, 0, zero_bytes, stream);

    // ---- CSR build (once, reused by all 3 layers) ----
    hist_kernel<<<(NE + 255) / 256, 256, 0, stream>>>(dst, cnt, NE);
    scan1_kernel<<<NNP / 256, 256, 0, stream>>>(cnt, row_ptr, bsum);
    scan2_kernel<<<1, 256, 0, stream>>>(bsum, NNP / 256);
    scan3_kernel<<<NNP / 256, 256, 0, stream>>>(row_ptr, bsum, fillc);
    fill_kernel<<<(NE + 255) / 256, 256, 0, stream>>>(src, dst, fillc, eidx, NE);

    // ---- layer 1 (project-then-gather): xp = x@W1l, xr = x@W1r + b1 ----
    gemm_kernel<128, 64, 64, 64, false, false, false, true>
        <<<dim3((NN + 63) / 64, 1), 256, 0, stream>>>(
        x, nullptr, W1l, W1r, b1, nullptr, xp, xr, nullptr, NN);
    gather_add_kernel<<<3125, 256, 0, stream>>>(xp, xr, row_ptr, eidx, h1, stats + 0);
    bnfin_kernel<<<1, 256, 0, stream>>>(stats + 0, g1, be1, ss1, 64, 1.0f / NN);

    // ---- layer 2: in 64 -> out 128 (h1 activated on the fly via ss1) ----
    gather_kernel<64, true><<<(NN * 16 + 255) / 256, 256, 0, stream>>>(
        h1, row_ptr, eidx, agg, ss1);
    gemm_kernel<64, 128, 128, 64, true, true, true, false>
        <<<dim3((NN + 63) / 64, 1), 256, 0, stream>>>(
        h1, agg, W2r, W2l, b2, ss1, h2, nullptr, stats + 512, NN);
    bnfin_kernel<<<1, 256, 0, stream>>>(stats + 512, g2, be2, ss2, 128, 1.0f / NN);

    // ---- layer 3: in 128 -> out 256 (h2 activated via ss2; N split over 2 blocks) ----
    gather_kernel<128, true><<<(NN * 32 + 255) / 256, 256, 0, stream>>>(
        h2, row_ptr, eidx, agg, ss2);
    gemm_kernel<128, 256, 128, 64, true, true, true, false>
        <<<dim3((NN + 63) / 64, 2), 256, 0, stream>>>(
        h2, agg, W3r, W3l, b3, ss2, h3, nullptr, stats + 1024, NN);
    bnfin_kernel<<<1, 256, 0, stream>>>(stats + 1024, g3, be3, ss3, 256, 1.0f / NN);

    // ---- projection: 256 -> 128 (h3 activated via ss3), straight to d_out ----
    gemm_kernel<256, 128, 128, 64, false, false, true, false>
        <<<dim3((NN + 63) / 64, 1), 256, 0, stream>>>(
        h3, nullptr, Wp, nullptr, bp, ss3, (float*)d_out, nullptr, nullptr, NN);
}

// Round 12
// 640.974 us; speedup vs baseline: 1.1173x; 1.1173x over previous
//
#include <hip/hip_runtime.h>

#define NN 50000
#define NE 800000
#define NNP 50176           // NN padded to 196*256
#define EPSV 1e-5f

// ---------------- CSR build: histogram ----------------
__global__ void hist_kernel(const int* __restrict__ dst, int* __restrict__ cnt, int ne) {
    int e = blockIdx.x * blockDim.x + threadIdx.x;
    if (e < ne) atomicAdd(&cnt[dst[e]], 1);
}

// ---------------- CSR build: 3-phase exclusive scan over NNP elements ----------------
__global__ void scan1_kernel(const int* __restrict__ cnt, int* __restrict__ row_ptr,
                             int* __restrict__ bsum) {
    __shared__ int s[256];
    int i = blockIdx.x * 256 + threadIdx.x;
    int v = cnt[i];
    s[threadIdx.x] = v;
    __syncthreads();
    #pragma unroll
    for (int off = 1; off < 256; off <<= 1) {
        int t = (threadIdx.x >= off) ? s[threadIdx.x - off] : 0;
        __syncthreads();
        s[threadIdx.x] += t;
        __syncthreads();
    }
    row_ptr[i] = s[threadIdx.x] - v;           // exclusive within block
    if (threadIdx.x == 255) bsum[blockIdx.x] = s[255];
}

__global__ void scan2_kernel(int* __restrict__ bsum, int nb) {
    __shared__ int s[256];
    int v = (threadIdx.x < nb) ? bsum[threadIdx.x] : 0;
    s[threadIdx.x] = v;
    __syncthreads();
    #pragma unroll
    for (int off = 1; off < 256; off <<= 1) {
        int t = (threadIdx.x >= off) ? s[threadIdx.x - off] : 0;
        __syncthreads();
        s[threadIdx.x] += t;
        __syncthreads();
    }
    if (threadIdx.x < nb) bsum[threadIdx.x] = s[threadIdx.x] - v;  // exclusive
}

__global__ void scan3_kernel(int* __restrict__ row_ptr, const int* __restrict__ bsum,
                             int* __restrict__ fill) {
    int i = blockIdx.x * 256 + threadIdx.x;
    int v = row_ptr[i] + bsum[blockIdx.x];
    row_ptr[i] = v;
    if (i < NN) fill[i] = v;   // running insert cursors start at row offsets
}

// ---------------- CSR build: bucket fill ----------------
__global__ void fill_kernel(const int* __restrict__ src, const int* __restrict__ dst,
                            int* __restrict__ fill, int* __restrict__ eidx, int ne) {
    int e = blockIdx.x * blockDim.x + threadIdx.x;
    if (e >= ne) return;
    int pos = atomicAdd(&fill[dst[e]], 1);
    eidx[pos] = src[e];
}

__device__ __forceinline__ void act4(float4& v, const float4& sc, const float4& sh) {
    v.x = fmaxf(fmaf(v.x, sc.x, sh.x), 0.f);
    v.y = fmaxf(fmaf(v.y, sc.y, sh.y), 0.f);
    v.z = fmaxf(fmaf(v.z, sc.z, sh.z), 0.f);
    v.w = fmaxf(fmaf(v.w, sc.w, sh.w), 0.f);
}
__device__ __forceinline__ void add4(float4& a, const float4& v) {
    a.x += v.x; a.y += v.y; a.z += v.z; a.w += v.w;
}

// ---------------- gather mean-aggregation (layers 2/3) ----------------
// agg[n] = mean_{s in adj(n)} act(x[s]); act = relu(v*sc+sh) if AFF.
// Edge loop unrolled x4, 4 accumulators for memory-level parallelism.
template<int F, bool AFF>
__global__ __launch_bounds__(256) void gather_kernel(
    const float* __restrict__ x, const int* __restrict__ row_ptr,
    const int* __restrict__ eidx, float* __restrict__ agg,
    const float* __restrict__ ss) {
    constexpr int TPN = F / 4;
    constexpr int NPB = 256 / TPN;
    int t = threadIdx.x;
    int node = blockIdx.x * NPB + t / TPN;
    if (node >= NN) return;
    int f = (t % TPN) * 4;
    float4 sc = make_float4(1.f, 1.f, 1.f, 1.f);
    float4 sh = make_float4(0.f, 0.f, 0.f, 0.f);
    if constexpr (AFF) {
        sc = *reinterpret_cast<const float4*>(&ss[f]);
        sh = *reinterpret_cast<const float4*>(&ss[F + f]);
    }
    int beg = row_ptr[node], end = row_ptr[node + 1];
    float4 a0 = make_float4(0.f,0.f,0.f,0.f), a1 = a0, a2 = a0, a3 = a0;
    int i = beg;
    for (; i + 3 < end; i += 4) {
        int s0 = eidx[i], s1 = eidx[i+1], s2 = eidx[i+2], s3 = eidx[i+3];
        float4 v0 = *reinterpret_cast<const float4*>(x + (size_t)s0 * F + f);
        float4 v1 = *reinterpret_cast<const float4*>(x + (size_t)s1 * F + f);
        float4 v2 = *reinterpret_cast<const float4*>(x + (size_t)s2 * F + f);
        float4 v3 = *reinterpret_cast<const float4*>(x + (size_t)s3 * F + f);
        if constexpr (AFF) { act4(v0,sc,sh); act4(v1,sc,sh); act4(v2,sc,sh); act4(v3,sc,sh); }
        add4(a0,v0); add4(a1,v1); add4(a2,v2); add4(a3,v3);
    }
    for (; i < end; i++) {
        int s0 = eidx[i];
        float4 v0 = *reinterpret_cast<const float4*>(x + (size_t)s0 * F + f);
        if constexpr (AFF) act4(v0,sc,sh);
        add4(a0,v0);
    }
    add4(a0,a1); add4(a2,a3); add4(a0,a2);
    float inv = 1.0f / (float)max(end - beg, 1);
    a0.x *= inv; a0.y *= inv; a0.z *= inv; a0.w *= inv;
    *reinterpret_cast<float4*>(agg + (size_t)node * F + f) = a0;
}

// ---------------- layer-1 gather-add: h1 = mean(xp[s]) + xr[n], + BN stats ----------------
// xp = x@W1l (no bias), xr = x@W1r + b1. F fixed at 64. Grid exactly 3125x256.
__global__ __launch_bounds__(256) void gather_add_kernel(
    const float* __restrict__ xp, const float* __restrict__ xr,
    const int* __restrict__ row_ptr, const int* __restrict__ eidx,
    float* __restrict__ h, float* __restrict__ stats) {
    __shared__ float sStat[128];
    int t = threadIdx.x;
    if (t < 128) sStat[t] = 0.f;
    __syncthreads();
    int node = blockIdx.x * 16 + t / 16;   // always < NN (grid exact)
    int f = (t % 16) * 4;
    int beg = row_ptr[node], end = row_ptr[node + 1];
    float4 a0 = make_float4(0.f,0.f,0.f,0.f), a1 = a0, a2 = a0, a3 = a0;
    int i = beg;
    for (; i + 3 < end; i += 4) {
        int s0 = eidx[i], s1 = eidx[i+1], s2 = eidx[i+2], s3 = eidx[i+3];
        add4(a0, *reinterpret_cast<const float4*>(xp + (size_t)s0 * 64 + f));
        add4(a1, *reinterpret_cast<const float4*>(xp + (size_t)s1 * 64 + f));
        add4(a2, *reinterpret_cast<const float4*>(xp + (size_t)s2 * 64 + f));
        add4(a3, *reinterpret_cast<const float4*>(xp + (size_t)s3 * 64 + f));
    }
    for (; i < end; i++)
        add4(a0, *reinterpret_cast<const float4*>(xp + (size_t)eidx[i] * 64 + f));
    add4(a0,a1); add4(a2,a3); add4(a0,a2);
    float inv = 1.0f / (float)max(end - beg, 1);
    float4 o = *reinterpret_cast<const float4*>(xr + (size_t)node * 64 + f);
    o.x = fmaf(a0.x, inv, o.x);
    o.y = fmaf(a0.y, inv, o.y);
    o.z = fmaf(a0.z, inv, o.z);
    o.w = fmaf(a0.w, inv, o.w);
    *reinterpret_cast<float4*>(h + (size_t)node * 64 + f) = o;
    atomicAdd(&sStat[f + 0], o.x);      atomicAdd(&sStat[64 + f + 0], o.x * o.x);
    atomicAdd(&sStat[f + 1], o.y);      atomicAdd(&sStat[64 + f + 1], o.y * o.y);
    atomicAdd(&sStat[f + 2], o.z);      atomicAdd(&sStat[64 + f + 2], o.z * o.z);
    atomicAdd(&sStat[f + 3], o.w);      atomicAdd(&sStat[64 + f + 3], o.w * o.w);
    __syncthreads();
    if (t < 128) unsafeAtomicAdd(&stats[t], sStat[t]);
}

// Macro params avoid collision with .x/.y/.z/.w member tokens.
#define FMA4(A_, W_, S_) { S_[0]=fmaf(A_,(W_).x,S_[0]); S_[1]=fmaf(A_,(W_).y,S_[1]); \
                           S_[2]=fmaf(A_,(W_).z,S_[2]); S_[3]=fmaf(A_,(W_).w,S_[3]); }

// ---------------- fused GEMM (round-9 staging: direct global->LDS, no reg prefetch) ----
// Normal:  y = agg@Wagg + bias + act(x)@Wroot (+BN stats).
// DUAL:    y = x@Wroot (no bias), y2 = x@Wagg + bias  (x staged once, two W mats).
template<int K, int N, int NB, int ROWS, bool HAS_AGG, bool BN, bool AFFX, bool DUAL>
__global__ __launch_bounds__(256, 4) void gemm_kernel(
    const float* __restrict__ xin, const float* __restrict__ agg,
    const float* __restrict__ Wroot, const float* __restrict__ Wagg,
    const float* __restrict__ bias, const float* __restrict__ ssx,
    float* __restrict__ y, float* __restrict__ y2,
    float* __restrict__ stats, int M)
{
    constexpr int  Kc = 16;
    constexpr int  CG = NB / 4;         // col groups (threads in col dim)
    constexpr int  RT = 256 / CG;       // row threads
    constexpr int  RPT = ROWS / RT;     // rows per thread
    constexpr int  XP = Kc + 4;         // padded LDS stride
    constexpr bool W2 = HAS_AGG || DUAL;

    __shared__ float sWr[Kc * NB];
    __shared__ float sWa[W2 ? Kc * NB : 1];
    __shared__ float sX [ROWS * XP];
    __shared__ float sA [HAS_AGG ? ROWS * XP : 1];
    __shared__ float sStat[BN ? 2 * NB : 1];

    const int tid  = threadIdx.x;
    const int tx   = tid % CG;
    const int ty   = tid / CG;
    const int row0 = blockIdx.x * ROWS;
    const int col0 = blockIdx.y * NB;

    float acc[RPT][4];
    float acc2[DUAL ? RPT : 1][4];
    #pragma unroll
    for (int i = 0; i < RPT; i++) { acc[i][0]=0.f; acc[i][1]=0.f; acc[i][2]=0.f; acc[i][3]=0.f; }
    if constexpr (DUAL) {
        #pragma unroll
        for (int i = 0; i < RPT; i++) { acc2[i][0]=0.f; acc2[i][1]=0.f; acc2[i][2]=0.f; acc2[i][3]=0.f; }
    }

    for (int k0 = 0; k0 < K; k0 += Kc) {
        // stage W chunk (Kc x NB) for both mats
        for (int idx = tid; idx < Kc * NB / 4; idx += 256) {
            int r = (idx * 4) / NB, c = (idx * 4) % NB;
            *reinterpret_cast<float4*>(&sWr[r * NB + c]) =
                *reinterpret_cast<const float4*>(&Wroot[(size_t)(k0 + r) * N + col0 + c]);
            if constexpr (W2)
                *reinterpret_cast<float4*>(&sWa[r * NB + c]) =
                    *reinterpret_cast<const float4*>(&Wagg[(size_t)(k0 + r) * N + col0 + c]);
        }
        // stage x / agg tile (ROWS x Kc); apply producing-layer BN+ReLU to x if AFFX
        for (int idx = tid; idx < ROWS * Kc / 4; idx += 256) {
            int r = idx / (Kc / 4);
            int c = (idx % (Kc / 4)) * 4;
            int grow = row0 + r;
            float4 xv = make_float4(0.f, 0.f, 0.f, 0.f);
            float4 av = make_float4(0.f, 0.f, 0.f, 0.f);
            if (grow < M) {
                xv = *reinterpret_cast<const float4*>(&xin[(size_t)grow * K + k0 + c]);
                if constexpr (AFFX) {
                    float4 sc = *reinterpret_cast<const float4*>(&ssx[k0 + c]);
                    float4 sh = *reinterpret_cast<const float4*>(&ssx[K + k0 + c]);
                    act4(xv, sc, sh);
                }
                if constexpr (HAS_AGG)
                    av = *reinterpret_cast<const float4*>(&agg[(size_t)grow * K + k0 + c]);
            }
            *reinterpret_cast<float4*>(&sX[r * XP + c]) = xv;
            if constexpr (HAS_AGG) *reinterpret_cast<float4*>(&sA[r * XP + c]) = av;
        }
        __syncthreads();

        #pragma unroll
        for (int kk0 = 0; kk0 < Kc; kk0 += 4) {
            float4 wr0 = *reinterpret_cast<const float4*>(&sWr[(kk0 + 0) * NB + tx * 4]);
            float4 wr1 = *reinterpret_cast<const float4*>(&sWr[(kk0 + 1) * NB + tx * 4]);
            float4 wr2 = *reinterpret_cast<const float4*>(&sWr[(kk0 + 2) * NB + tx * 4]);
            float4 wr3 = *reinterpret_cast<const float4*>(&sWr[(kk0 + 3) * NB + tx * 4]);
            float4 wa0, wa1, wa2, wa3;
            if constexpr (W2) {
                wa0 = *reinterpret_cast<const float4*>(&sWa[(kk0 + 0) * NB + tx * 4]);
                wa1 = *reinterpret_cast<const float4*>(&sWa[(kk0 + 1) * NB + tx * 4]);
                wa2 = *reinterpret_cast<const float4*>(&sWa[(kk0 + 2) * NB + tx * 4]);
                wa3 = *reinterpret_cast<const float4*>(&sWa[(kk0 + 3) * NB + tx * 4]);
            }
            #pragma unroll
            for (int i = 0; i < RPT; i++) {
                int r = ty + i * RT;
                float4 xv = *reinterpret_cast<const float4*>(&sX[r * XP + kk0]);
                FMA4(xv.x, wr0, acc[i]);
                FMA4(xv.y, wr1, acc[i]);
                FMA4(xv.z, wr2, acc[i]);
                FMA4(xv.w, wr3, acc[i]);
                if constexpr (HAS_AGG) {
                    float4 av = *reinterpret_cast<const float4*>(&sA[r * XP + kk0]);
                    FMA4(av.x, wa0, acc[i]);
                    FMA4(av.y, wa1, acc[i]);
                    FMA4(av.z, wa2, acc[i]);
                    FMA4(av.w, wa3, acc[i]);
                } else if constexpr (DUAL) {
                    FMA4(xv.x, wa0, acc2[i]);
                    FMA4(xv.y, wa1, acc2[i]);
                    FMA4(xv.z, wa2, acc2[i]);
                    FMA4(xv.w, wa3, acc2[i]);
                }
            }
        }
        __syncthreads();
    }

    float4 bv = *reinterpret_cast<const float4*>(&bias[col0 + tx * 4]);

    if constexpr (DUAL) {
        #pragma unroll
        for (int i = 0; i < RPT; i++) {
            int grow = row0 + ty + i * RT;
            if (grow < M) {
                float4 o1 = make_float4(acc[i][0], acc[i][1], acc[i][2], acc[i][3]);
                float4 o2 = make_float4(acc2[i][0] + bv.x, acc2[i][1] + bv.y,
                                        acc2[i][2] + bv.z, acc2[i][3] + bv.w);
                *reinterpret_cast<float4*>(&y [(size_t)grow * N + col0 + tx * 4]) = o1;
                *reinterpret_cast<float4*>(&y2[(size_t)grow * N + col0 + tx * 4]) = o2;
            }
        }
        return;
    }

    if constexpr (BN) {
        for (int idx = tid; idx < 2 * NB; idx += 256) sStat[idx] = 0.f;
        __syncthreads();
    }

    float cs[4] = {0.f,0.f,0.f,0.f}, cq[4] = {0.f,0.f,0.f,0.f};
    #pragma unroll
    for (int i = 0; i < RPT; i++) {
        int grow = row0 + ty + i * RT;
        if (grow < M) {
            float4 o;
            o.x = acc[i][0] + bv.x;
            o.y = acc[i][1] + bv.y;
            o.z = acc[i][2] + bv.z;
            o.w = acc[i][3] + bv.w;
            *reinterpret_cast<float4*>(&y[(size_t)grow * N + col0 + tx * 4]) = o;
            if constexpr (BN) {
                cs[0] += o.x; cq[0] += o.x * o.x;
                cs[1] += o.y; cq[1] += o.y * o.y;
                cs[2] += o.z; cq[2] += o.z * o.z;
                cs[3] += o.w; cq[3] += o.w * o.w;
            }
        }
    }

    if constexpr (BN) {
        atomicAdd(&sStat[tx * 4 + 0], cs[0]);
        atomicAdd(&sStat[tx * 4 + 1], cs[1]);
        atomicAdd(&sStat[tx * 4 + 2], cs[2]);
        atomicAdd(&sStat[tx * 4 + 3], cs[3]);
        atomicAdd(&sStat[NB + tx * 4 + 0], cq[0]);
        atomicAdd(&sStat[NB + tx * 4 + 1], cq[1]);
        atomicAdd(&sStat[NB + tx * 4 + 2], cq[2]);
        atomicAdd(&sStat[NB + tx * 4 + 3], cq[3]);
        __syncthreads();
        for (int idx = tid; idx < 2 * NB; idx += 256) {
            int gidx = (idx < NB) ? (col0 + idx) : (N + col0 + idx - NB);
            unsafeAtomicAdd(&stats[gidx], sStat[idx]);
        }
    }
}

// ---------------- BN finalize: scale/shift per column ----------------
__global__ void bnfin_kernel(const float* __restrict__ stats, const float* __restrict__ g,
                             const float* __restrict__ be, float* __restrict__ ss,
                             int N, float invM) {
    int c = threadIdx.x;
    if (c >= N) return;
    float mean = stats[c] * invM;
    float var  = stats[N + c] * invM - mean * mean;
    float sc   = g[c] * rsqrtf(fmaxf(var, 0.f) + EPSV);
    ss[c]     = sc;
    ss[N + c] = be[c] - mean * sc;
}

extern "C" void kernel_launch(void* const* d_in, const int* in_sizes, int n_in,
                              void* d_out, int out_size, void* d_ws, size_t ws_size,
                              hipStream_t stream) {
    const float* x   = (const float*)d_in[0];
    const int*   ei  = (const int*)d_in[1];
    const int*   src = ei;
    const int*   dst = ei + NE;
    const float *W1l = (const float*)d_in[2],  *b1 = (const float*)d_in[3],
                *W1r = (const float*)d_in[4],  *g1 = (const float*)d_in[5],  *be1 = (const float*)d_in[6];
    const float *W2l = (const float*)d_in[7],  *b2 = (const float*)d_in[8],
                *W2r = (const float*)d_in[9],  *g2 = (const float*)d_in[10], *be2 = (const float*)d_in[11];
    const float *W3l = (const float*)d_in[12], *b3 = (const float*)d_in[13],
                *W3r = (const float*)d_in[14], *g3 = (const float*)d_in[15], *be3 = (const float*)d_in[16];
    const float *Wp  = (const float*)d_in[17], *bp = (const float*)d_in[18];

    char* w = (char*)d_ws;
    size_t off = 0;
    auto alloc = [&](size_t bytes) { char* p = w + off; off += (bytes + 255) & ~255ULL; return p; };

    int*   cnt     = (int*)  alloc(NNP * 4);          // zeroed
    float* stats   = (float*)alloc(1536 * 4);         // zeroed
    size_t zero_bytes = off;
    float* ss      = (float*)alloc(1536 * 4);
    int*   row_ptr = (int*)  alloc((NNP + 1) * 4);
    int*   fillc   = (int*)  alloc(NNP * 4);
    int*   bsum    = (int*)  alloc(256 * 4);
    int*   eidx    = (int*)  alloc((size_t)NE * 4);
    float* agg     = (float*)alloc((size_t)NN * 128 * 4);
    float* h1      = (float*)alloc((size_t)NN * 64 * 4);
    float* h2      = (float*)alloc((size_t)NN * 128 * 4);
    float* h3      = (float*)alloc((size_t)NN * 256 * 4);

    float* ss1 = ss + 0;     // [64 sc | 64 sh]
    float* ss2 = ss + 512;   // [128 sc | 128 sh]
    float* ss3 = ss + 1024;  // [256 sc | 256 sh]
    float* xp  = agg;                    // NN*64, dead before L2 gather reuses agg
    float* xr  = agg + (size_t)NN * 64;  // NN*64

    (void)hipMemsetAsync(d_ws, 0, zero_bytes, stream);

    // ---- CSR build (once, reused by all 3 layers) ----
    hist_kernel<<<(NE + 255) / 256, 256, 0, stream>>>(dst, cnt, NE);
    scan1_kernel<<<NNP / 256, 256, 0, stream>>>(cnt, row_ptr, bsum);
    scan2_kernel<<<1, 256, 0, stream>>>(bsum, NNP / 256);
    scan3_kernel<<<NNP / 256, 256, 0, stream>>>(row_ptr, bsum, fillc);
    fill_kernel<<<(NE + 255) / 256, 256, 0, stream>>>(src, dst, fillc, eidx, NE);

    // ---- layer 1 (project-then-gather): xp = x@W1l, xr = x@W1r + b1 ----
    gemm_kernel<128, 64, 64, 64, false, false, false, true>
        <<<dim3((NN + 63) / 64, 1), 256, 0, stream>>>(
        x, nullptr, W1l, W1r, b1, nullptr, xp, xr, nullptr, NN);
    gather_add_kernel<<<3125, 256, 0, stream>>>(xp, xr, row_ptr, eidx, h1, stats + 0);
    bnfin_kernel<<<1, 256, 0, stream>>>(stats + 0, g1, be1, ss1, 64, 1.0f / NN);

    // ---- layer 2: in 64 -> out 128 (h1 activated on the fly via ss1) ----
    gather_kernel<64, true><<<(NN * 16 + 255) / 256, 256, 0, stream>>>(
        h1, row_ptr, eidx, agg, ss1);
    gemm_kernel<64, 128, 128, 64, true, true, true, false>
        <<<dim3((NN + 63) / 64, 1), 256, 0, stream>>>(
        h1, agg, W2r, W2l, b2, ss1, h2, nullptr, stats + 512, NN);
    bnfin_kernel<<<1, 256, 0, stream>>>(stats + 512, g2, be2, ss2, 128, 1.0f / NN);

    // ---- layer 3: in 128 -> out 256 (h2 activated via ss2; N split over 2 blocks) ----
    gather_kernel<128, true><<<(NN * 32 + 255) / 256, 256, 0, stream>>>(
        h2, row_ptr, eidx, agg, ss2);
    gemm_kernel<128, 256, 128, 64, true, true, true, false>
        <<<dim3((NN + 63) / 64, 2), 256, 0, stream>>>(
        h2, agg, W3r, W3l, b3, ss2, h3, nullptr, stats + 1024, NN);
    bnfin_kernel<<<1, 256, 0, stream>>>(stats + 1024, g3, be3, ss3, 256, 1.0f / NN);

    // ---- projection: 256 -> 128 (h3 activated via ss3), straight to d_out ----
    gemm_kernel<256, 128, 128, 64, false, false, true, false>
        <<<dim3((NN + 63) / 64, 1), 256, 0, stream>>>(
        h3, nullptr, Wp, nullptr, bp, ss3, (float*)d_out, nullptr, nullptr, NN);
}